// Round 2
// baseline (246.520 us; speedup 1.0000x reference)
//
#include <hip/hip_runtime.h>

// ---------------------------------------------------------------------------
// MaskAttentionHead: x[4,4096,1024] fp32, Wq/Wk/Wv[64,1024] fp32 ->
// out[4,4096,64] fp32.  q,k,v = x@W^T; att = softmax(causal(q k^T / 8)); out = att v.
// Strategy: bf16 MFMA throughout (threshold 3.08e-2 permits), flash-style
// online softmax (never materialize 4096x4096 scores).
// ws layout (bf16/u16): Wb[192*1024] | Q[16384*64] | K[16384*64] | Vt[4*64*4096]
// total ~6.4 MB.
// ---------------------------------------------------------------------------

typedef __attribute__((ext_vector_type(8))) short v8s;   // 8 x bf16 (4 VGPRs)
typedef __attribute__((ext_vector_type(4))) float v4f;   // MFMA 16x16 C/D

static __device__ __forceinline__ unsigned short f2bf(float x) {
  unsigned int u = __builtin_bit_cast(unsigned int, x);
  u += 0x7fffu + ((u >> 16) & 1u);          // round-to-nearest-even
  return (unsigned short)(u >> 16);
}

// --- kernel 1: pack weights to bf16; fold softmax scale (1/8) into Wq ------
__global__ __launch_bounds__(256) void pack_w(const float* __restrict__ Wq,
                                              const float* __restrict__ Wk,
                                              const float* __restrict__ Wv,
                                              unsigned short* __restrict__ Wb) {
  int idx = (blockIdx.x * 256 + threadIdx.x) * 4;  // 192*1024 elements total
  int row = idx >> 10;
  int col = idx & 1023;
  const float* src;
  float scale;
  if (row < 64)       { src = Wq + row * 1024 + col;        scale = 0.125f; }
  else if (row < 128) { src = Wk + (row - 64) * 1024 + col; scale = 1.0f;   }
  else                { src = Wv + (row - 128) * 1024 + col; scale = 1.0f;  }
  float4 f = *(const float4*)src;
  ushort4 o;
  o.x = f2bf(f.x * scale); o.y = f2bf(f.y * scale);
  o.z = f2bf(f.z * scale); o.w = f2bf(f.w * scale);
  *(ushort4*)(Wb + idx) = o;
}

// --- kernel 2: fused QKV projection ----------------------------------------
// M=16384 rows, N=192 (q|k|v heads), K=1024.  256 blocks x 64 rows.
// 4 waves, wave w owns rows w*16..w*16+16.  16x16x32 bf16 MFMA.
__global__ __launch_bounds__(256) void qkv(const float* __restrict__ x,
                                           const unsigned short* __restrict__ Wb,
                                           unsigned short* __restrict__ Qg,
                                           unsigned short* __restrict__ Kg,
                                           unsigned short* __restrict__ Vt) {
  __shared__ alignas(16) unsigned short xl[64 * 72];    // x tile, pad 72 (2-way free)
  __shared__ alignas(16) unsigned short wl[192 * 72];   // W chunk
  const int tid   = threadIdx.x;
  const int lane  = tid & 63;
  const int wv    = tid >> 6;
  const int quad  = lane >> 4;
  const int colid = lane & 15;
  const int m0    = blockIdx.x * 64;

  v4f acc[12];
#pragma unroll
  for (int i = 0; i < 12; i++) acc[i] = (v4f){0.f, 0.f, 0.f, 0.f};

  for (int kc = 0; kc < 1024; kc += 64) {
    // stage x[m0:m0+64][kc:kc+64] fp32 -> bf16 LDS (coalesced 256B/row)
#pragma unroll
    for (int i = tid; i < 64 * 16; i += 256) {
      int r = i >> 4, c = (i & 15) * 4;
      float4 f = *(const float4*)(x + (size_t)(m0 + r) * 1024 + kc + c);
      ushort4 u;
      u.x = f2bf(f.x); u.y = f2bf(f.y); u.z = f2bf(f.z); u.w = f2bf(f.w);
      *(ushort4*)(&xl[r * 72 + c]) = u;
    }
    // stage Wb[0:192][kc:kc+64] bf16 LDS
#pragma unroll
    for (int i = tid; i < 192 * 8; i += 256) {
      int r = i >> 3, c = (i & 7) * 8;
      int4 w = *(const int4*)(Wb + (size_t)r * 1024 + kc + c);
      *(int4*)(&wl[r * 72 + c]) = w;
    }
    __syncthreads();
#pragma unroll
    for (int ks = 0; ks < 64; ks += 32) {
      v8s a = *(const v8s*)(&xl[(wv * 16 + colid) * 72 + ks + quad * 8]);
#pragma unroll
      for (int nt = 0; nt < 12; nt++) {
        v8s b = *(const v8s*)(&wl[(nt * 16 + colid) * 72 + ks + quad * 8]);
        acc[nt] = __builtin_amdgcn_mfma_f32_16x16x32_bf16(a, b, acc[nt], 0, 0, 0);
      }
    }
    __syncthreads();
  }

  // epilogue: C/D row = quad*4+reg, col = colid
  const int trow_base = m0 + wv * 16 + quad * 4;
#pragma unroll
  for (int nt = 0; nt < 4; nt++)
#pragma unroll
    for (int r = 0; r < 4; r++) {
      int t = trow_base + r;
      Qg[(size_t)t * 64 + nt * 16 + colid] = f2bf(acc[nt][r]);
    }
#pragma unroll
  for (int nt = 0; nt < 4; nt++)
#pragma unroll
    for (int r = 0; r < 4; r++) {
      int t = trow_base + r;
      Kg[(size_t)t * 64 + nt * 16 + colid] = f2bf(acc[4 + nt][r]);
    }
#pragma unroll
  for (int nt = 0; nt < 4; nt++)
#pragma unroll
    for (int r = 0; r < 4; r++) {
      int t = trow_base + r;
      int b = t >> 12, tt = t & 4095;
      Vt[(size_t)b * (64 * 4096) + (size_t)(nt * 16 + colid) * 4096 + tt] =
          f2bf(acc[8 + nt][r]);
    }
}

// --- kernel 3: causal flash attention --------------------------------------
// grid (64 q-tiles, 4 batches); 4 waves x 16 Q-rows (BM=64); BN=64 KV tiles.
__global__ __launch_bounds__(256) void flash(const unsigned short* __restrict__ Qg,
                                             const unsigned short* __restrict__ Kg,
                                             const unsigned short* __restrict__ Vt,
                                             float* __restrict__ out) {
  __shared__ alignas(16) unsigned short kl[64 * 72];        // K tile [s][h]
  __shared__ alignas(16) unsigned short vl[64 * 72];        // V tile [h][s]
  __shared__ alignas(16) unsigned short pl[4][16 * 72];     // per-wave P [t][s]

  const int tid   = threadIdx.x;
  const int lane  = tid & 63;
  const int wv    = tid >> 6;
  const int quad  = lane >> 4;
  const int colid = lane & 15;
  const int qi    = blockIdx.x;
  const int b     = blockIdx.y;
  const size_t bT = (size_t)b * 4096;
  const int t0    = qi * 64 + wv * 16;   // wave's Q rows (batch-local)

  // Q fragments (A-operand): lane holds Q[t0+colid][quad*8+j (+32)]
  v8s qf0 = *(const v8s*)(Qg + (bT + t0 + colid) * 64 + quad * 8);
  v8s qf1 = *(const v8s*)(Qg + (bT + t0 + colid) * 64 + 32 + quad * 8);

  v4f o[4];
#pragma unroll
  for (int i = 0; i < 4; i++) o[i] = (v4f){0.f, 0.f, 0.f, 0.f};
  float m_i[4], l_i[4];
#pragma unroll
  for (int r = 0; r < 4; r++) { m_i[r] = -1e30f; l_i[r] = 0.f; }

  // staging indices: 4 threads/row, 32 B each
  const int sr = tid >> 2;
  const int sc = (tid & 3) * 16;

  for (int si = 0; si <= qi; si++) {
    {
      const int4* ksrc = (const int4*)(Kg + (bT + si * 64 + sr) * 64 + sc);
      *(int4*)(&kl[sr * 72 + sc]) = ksrc[0];
      *(int4*)(&kl[sr * 72 + sc + 8]) = ksrc[1];
      const int4* vsrc =
          (const int4*)(Vt + (size_t)b * (64 * 4096) + (size_t)sr * 4096 + si * 64 + sc);
      *(int4*)(&vl[sr * 72 + sc]) = vsrc[0];
      *(int4*)(&vl[sr * 72 + sc + 8]) = vsrc[1];
    }
    __syncthreads();

    // S = Q K^T  (scale pre-folded into Wq)
    v4f s[4];
#pragma unroll
    for (int i = 0; i < 4; i++) s[i] = (v4f){0.f, 0.f, 0.f, 0.f};
#pragma unroll
    for (int nt = 0; nt < 4; nt++) {
      v8s b0 = *(const v8s*)(&kl[(nt * 16 + colid) * 72 + 0 + quad * 8]);
      s[nt] = __builtin_amdgcn_mfma_f32_16x16x32_bf16(qf0, b0, s[nt], 0, 0, 0);
      v8s b1 = *(const v8s*)(&kl[(nt * 16 + colid) * 72 + 32 + quad * 8]);
      s[nt] = __builtin_amdgcn_mfma_f32_16x16x32_bf16(qf1, b1, s[nt], 0, 0, 0);
    }

    // causal mask (diagonal tile only; BM==BN aligned)
    if (si == qi) {
      int trow = wv * 16 + quad * 4;
#pragma unroll
      for (int nt = 0; nt < 4; nt++)
#pragma unroll
        for (int r = 0; r < 4; r++)
          if (nt * 16 + colid > trow + r) s[nt][r] = -1e30f;
    }

    // online softmax: row = quad*4+reg; reduce over 16 lanes in quad-group
    float mx[4];
#pragma unroll
    for (int r = 0; r < 4; r++)
      mx[r] = fmaxf(fmaxf(s[0][r], s[1][r]), fmaxf(s[2][r], s[3][r]));
#pragma unroll
    for (int d = 1; d < 16; d <<= 1)
#pragma unroll
      for (int r = 0; r < 4; r++) mx[r] = fmaxf(mx[r], __shfl_xor(mx[r], d, 64));

    float alpha[4];
#pragma unroll
    for (int r = 0; r < 4; r++) {
      float mn = fmaxf(m_i[r], mx[r]);
      alpha[r] = __expf(m_i[r] - mn);
      m_i[r] = mn;
    }
    float rs[4] = {0.f, 0.f, 0.f, 0.f};
#pragma unroll
    for (int nt = 0; nt < 4; nt++)
#pragma unroll
      for (int r = 0; r < 4; r++) {
        float p = __expf(s[nt][r] - m_i[r]);
        s[nt][r] = p;
        rs[r] += p;
      }
#pragma unroll
    for (int d = 1; d < 16; d <<= 1)
#pragma unroll
      for (int r = 0; r < 4; r++) rs[r] += __shfl_xor(rs[r], d, 64);
#pragma unroll
    for (int r = 0; r < 4; r++) l_i[r] = l_i[r] * alpha[r] + rs[r];
#pragma unroll
    for (int nt = 0; nt < 4; nt++)
#pragma unroll
      for (int r = 0; r < 4; r++) o[nt][r] *= alpha[r];

    // P: C/D layout -> LDS [t][s] (wave-private) -> A-operand reads
    unsigned short* pw = pl[wv];
#pragma unroll
    for (int nt = 0; nt < 4; nt++)
#pragma unroll
      for (int r = 0; r < 4; r++)
        pw[(quad * 4 + r) * 72 + nt * 16 + colid] = f2bf(s[nt][r]);

    // O += P V   (B[k=s][n=h] = V[s][h] = vl[h][s], contiguous in s)
#pragma unroll
    for (int ks = 0; ks < 64; ks += 32) {
      v8s af = *(const v8s*)(&pw[colid * 72 + ks + quad * 8]);
#pragma unroll
      for (int nt = 0; nt < 4; nt++) {
        v8s bf = *(const v8s*)(&vl[(nt * 16 + colid) * 72 + ks + quad * 8]);
        o[nt] = __builtin_amdgcn_mfma_f32_16x16x32_bf16(af, bf, o[nt], 0, 0, 0);
      }
    }
    __syncthreads();
  }

  // epilogue: out[b][t][h] fp32
#pragma unroll
  for (int r = 0; r < 4; r++) {
    float inv = 1.0f / l_i[r];
    size_t trow = bT + (size_t)qi * 64 + wv * 16 + quad * 4 + r;
#pragma unroll
    for (int nt = 0; nt < 4; nt++)
      out[trow * 64 + nt * 16 + colid] = o[nt][r] * inv;
  }
}

extern "C" void kernel_launch(void* const* d_in, const int* in_sizes, int n_in,
                              void* d_out, int out_size, void* d_ws, size_t ws_size,
                              hipStream_t stream) {
  const float* x  = (const float*)d_in[0];
  const float* Wq = (const float*)d_in[1];
  const float* Wk = (const float*)d_in[2];
  const float* Wv = (const float*)d_in[3];
  float* out = (float*)d_out;

  unsigned short* Wb = (unsigned short*)d_ws;          // 192*1024
  unsigned short* Qg = Wb + 192 * 1024;                // 16384*64
  unsigned short* Kg = Qg + 16384 * 64;                // 16384*64
  unsigned short* Vt = Kg + 16384 * 64;                // 4*64*4096

  hipLaunchKernelGGL(pack_w, dim3(192), dim3(256), 0, stream, Wq, Wk, Wv, Wb);
  hipLaunchKernelGGL(qkv, dim3(256), dim3(256), 0, stream, x, Wb, Qg, Kg, Vt);
  hipLaunchKernelGGL(flash, dim3(64, 4), dim3(256), 0, stream, Qg, Kg, Vt, out);
}